// Round 9
// baseline (216.115 us; speedup 1.0000x reference)
//
#include <hip/hip_runtime.h>
#include <hip/hip_bf16.h>
#include <math.h>

typedef unsigned short u16;
typedef short bf16x8 __attribute__((ext_vector_type(8)));
typedef float f32x4 __attribute__((ext_vector_type(4)));

__device__ __forceinline__ u16 f2b(float f) {
    __hip_bfloat16 h = __float2bfloat16(f);
    return *reinterpret_cast<u16*>(&h);
}
__device__ __forceinline__ float b2f(u16 v) {
    __hip_bfloat16 h;
    *reinterpret_cast<u16*>(&h) = v;
    return __bfloat162float(h);
}

__device__ __forceinline__ void gload_lds16(const void* g, void* l) {
    __builtin_amdgcn_global_load_lds(
        (const __attribute__((address_space(1))) void*)g,
        (__attribute__((address_space(3))) void*)l, 16, 0, 0);
}

// ---------------- epilogues ----------------

struct EpiQKV4 {
    u16 *Q, *Kt, *Vt;
    __device__ void operator()(int rowp, int colp, f32x4 vals) const {
        int b = colp >> 9, pos = colp & 511;
        int sec = rowp >> 10, cc = rowp & 1023;
        int head = cc >> 6, d0 = cc & 63;
        ushort4 o;
        if (sec == 0) {
            if (pos < 256) return;
            o.x = f2b(vals[0] * 0.125f); o.y = f2b(vals[1] * 0.125f);
            o.z = f2b(vals[2] * 0.125f); o.w = f2b(vals[3] * 0.125f);
            *(ushort4*)(Q + (long)((head * 8 + b) * 256 + (pos - 256)) * 64 + d0) = o;
        } else {
            u16* dst = (sec == 1) ? Kt : Vt;
            o.x = f2b(vals[0]); o.y = f2b(vals[1]);
            o.z = f2b(vals[2]); o.w = f2b(vals[3]);
            *(ushort4*)(dst + (long)((b * 16 + head) * 512 + pos) * 64 + d0) = o;
        }
    }
};

struct EpiStoreBf {
    u16* C; long ldc; long strideZ;
    __device__ void operator()(int z, int row, int col, float val) const {
        C[(long)z * strideZ + (long)row * ldc + col] = f2b(val);
    }
};

struct EpiStoreF32 {
    float* C; long ldc;
    __device__ void operator()(int z, int row, int col, float val) const {
        C[(long)row * ldc + col] = val;
    }
};

// ---------------- 64x64-tile GEMM body (C = A @ B^T), LDS-staged ----------------
// Requires 14336 bytes of smem (2 x 64 x 56 x 2B).

template <typename Epi, bool AF32, bool ADDA, bool ROWMAP>
__device__ __forceinline__ void gemm_bt_body(char* smem, int bx, int by, int bz,
                                             const void* __restrict__ Av, int lda, long strideAz,
                                             const u16* __restrict__ B, int ldb, long strideBz,
                                             int K, Epi epi, const float* __restrict__ av) {
    constexpr int LDT = 56;
    u16* As = (u16*)smem;
    u16* Bs = As + 64 * LDT;
    int n0 = bx * 64, m0 = by * 64, z = bz;
    const u16* Bb = B + (long)z * strideBz + (long)n0 * ldb;
    int tid = threadIdx.x;
    int wave = tid >> 6, lane = tid & 63;
    int wm = wave >> 1, wn = wave & 1;
    int lrow = lane & 15, lquad = lane >> 4;
    int srow = tid >> 2, scol = (tid & 3) * 8;
    f32x4 acc[2][2] = {};
    for (int k0 = 0; k0 < K; k0 += 32) {
        if constexpr (AF32) {
            long arow = m0 + srow;
            if constexpr (ROWMAP) arow = (arow < 256) ? 768 + arow : 0;
            const float* src = (const float*)Av + (long)z * strideAz + arow * lda + k0 + scol;
            float4 f0 = *(const float4*)src;
            float4 f1 = *(const float4*)(src + 4);
            bf16x8 vv;
            vv[0] = (short)f2b(f0.x); vv[1] = (short)f2b(f0.y);
            vv[2] = (short)f2b(f0.z); vv[3] = (short)f2b(f0.w);
            vv[4] = (short)f2b(f1.x); vv[5] = (short)f2b(f1.y);
            vv[6] = (short)f2b(f1.z); vv[7] = (short)f2b(f1.w);
            *(bf16x8*)(As + srow * LDT + scol) = vv;
        } else {
            const u16* Ab = (const u16*)Av + (long)z * strideAz + (long)m0 * lda;
            *(bf16x8*)(As + srow * LDT + scol) = *(const bf16x8*)(Ab + (long)srow * lda + k0 + scol);
        }
        *(bf16x8*)(Bs + srow * LDT + scol) = *(const bf16x8*)(Bb + (long)srow * ldb + k0 + scol);
        __syncthreads();
        bf16x8 af[2], bfr[2];
        #pragma unroll
        for (int mt = 0; mt < 2; ++mt) {
            af[mt] = *(const bf16x8*)(As + (wm * 32 + mt * 16 + lrow) * LDT + lquad * 8);
            if constexpr (ADDA) {
                #pragma unroll
                for (int j = 0; j < 8; ++j)
                    af[mt][j] = (short)f2b(b2f((u16)af[mt][j]) + 0.125f * av[k0 + lquad * 8 + j]);
            }
        }
        #pragma unroll
        for (int nt = 0; nt < 2; ++nt)
            bfr[nt] = *(const bf16x8*)(Bs + (wn * 32 + nt * 16 + lrow) * LDT + lquad * 8);
        #pragma unroll
        for (int mt = 0; mt < 2; ++mt)
            #pragma unroll
            for (int nt = 0; nt < 2; ++nt)
                acc[mt][nt] = __builtin_amdgcn_mfma_f32_16x16x32_bf16(af[mt], bfr[nt], acc[mt][nt], 0, 0, 0);
        __syncthreads();
    }
    #pragma unroll
    for (int mt = 0; mt < 2; ++mt)
        #pragma unroll
        for (int nt = 0; nt < 2; ++nt)
            #pragma unroll
            for (int r = 0; r < 4; ++r) {
                int row = m0 + wm * 32 + mt * 16 + lquad * 4 + r;
                int col = n0 + wn * 32 + nt * 16 + lrow;
                epi(z, row, col, acc[mt][nt][r]);
            }
}

// ---------------- prep: cast_cat + all three weight transposes ----------------
__global__ __launch_bounds__(256) void prep_kernel(const float* __restrict__ x,
                                                   const float* __restrict__ h,
                                                   u16* __restrict__ catBF,
                                                   const float* __restrict__ Wqkv, u16* __restrict__ WqkvT,
                                                   const float* __restrict__ Wkr,  u16* __restrict__ WkrT,
                                                   const float* __restrict__ Wout, u16* __restrict__ WoutT) {
    __shared__ float tile[32][33];
    int bid = blockIdx.x, tid = threadIdx.x;
    if (bid < 2048) {
        int idx = (bid * 256 + tid) * 8;
        int c = idx & 1023, r = idx >> 10;
        int b = r >> 9, pos = r & 511;
        const float* src = (pos < 256) ? h + ((long)(b * 256 + pos) * 1024 + c)
                                       : x + ((long)(b * 256 + pos - 256) * 1024 + c);
        float4 f0 = *(const float4*)src;
        float4 f1 = *(const float4*)(src + 4);
        bf16x8 vv;
        vv[0] = (short)f2b(f0.x); vv[1] = (short)f2b(f0.y);
        vv[2] = (short)f2b(f0.z); vv[3] = (short)f2b(f0.w);
        vv[4] = (short)f2b(f1.x); vv[5] = (short)f2b(f1.y);
        vv[6] = (short)f2b(f1.z); vv[7] = (short)f2b(f1.w);
        *(bf16x8*)(catBF + idx) = vv;
        return;
    }
    const float* W; u16* WT; int nb, kb;
    if (bid < 5120) {
        int w = bid - 2048;  // 96 x 32 tiles
        W = Wqkv; WT = WqkvT;
        nb = (w % 96) * 32; kb = (w / 96) * 32;
        int tx = tid & 31, ty = tid >> 5;
        #pragma unroll
        for (int i = 0; i < 32; i += 8)
            tile[ty + i][tx] = W[(long)(kb + ty + i) * 3072 + nb + tx];
    } else {
        int w = bid - 5120;
        if (w < 1024) { W = Wkr; WT = WkrT; }
        else          { W = Wout; WT = WoutT; w -= 1024; }
        nb = (w & 31) * 32; kb = (w >> 5) * 32;
        int tx = tid & 31, ty = tid >> 5;
        #pragma unroll
        for (int i = 0; i < 32; i += 8)
            tile[ty + i][tx] = W[(long)(kb + ty + i) * 1024 + nb + tx];
    }
    __syncthreads();
    int row = tid >> 3;
    int c4 = (tid & 7) * 4;
    ushort4 o;
    o.x = f2b(tile[c4 + 0][row]);
    o.y = f2b(tile[c4 + 1][row]);
    o.z = f2b(tile[c4 + 2][row]);
    o.w = f2b(tile[c4 + 3][row]);
    *(ushort4*)(WT + (long)(nb + row) * 1024 + kb + c4) = o;
}

// ---------------- QKV GEMM (BK=32, m97 structure) + RWg GEMM ----------------
// bid < 768: QKV^T 128x128 tile (A=WqkvT 3072 rows, B=catBF 4096 rows).
// bid >= 768: RWg = (live R rows) @ WkrT, 80 blocks of 64x64.
__global__ __launch_bounds__(256) void qkv_rwg_kernel(const u16* __restrict__ A, const u16* __restrict__ B,
                                                      EpiQKV4 eq,
                                                      const float* __restrict__ R, const u16* __restrict__ WkrT,
                                                      u16* __restrict__ RWg) {
    __shared__ alignas(16) char smem[16384];   // QKV: 2x[128][32] bf16; RWg body: 14336
    int bid = blockIdx.x;
    if (bid >= 768) {
        int bid2 = bid - 768;
        gemm_bt_body<EpiStoreBf, true, false, true>(smem, bid2 & 15, bid2 >> 4, 0,
            (const void*)R, 1024, 0L, WkrT, 1024, 0L, 1024, EpiStoreBf{RWg, 1024, 0}, nullptr);
        return;
    }
    int n0 = (bid & 31) * 128, m0 = (bid >> 5) * 128;
    u16* As = (u16*)smem;          // [128][32] contiguous
    u16* Bs = As + 4096;
    int tid = threadIdx.x, wave = tid >> 6, lane = tid & 63;
    int wm = wave >> 1, wn = wave & 1;
    int lrow = lane & 15, lquad = lane >> 4;
    int grow = tid >> 2, gcol = (tid & 3) * 8;
    const u16* Ab = A + (long)m0 * 1024;
    const u16* Bb = B + (long)n0 * 1024;
    f32x4 acc[4][4] = {};
    for (int k0 = 0; k0 < 1024; k0 += 32) {
        gload_lds16(Ab + (long)grow * 1024 + k0 + gcol,        As + grow * 32 + gcol);
        gload_lds16(Ab + (long)(grow + 64) * 1024 + k0 + gcol, As + (grow + 64) * 32 + gcol);
        gload_lds16(Bb + (long)grow * 1024 + k0 + gcol,        Bs + grow * 32 + gcol);
        gload_lds16(Bb + (long)(grow + 64) * 1024 + k0 + gcol, Bs + (grow + 64) * 32 + gcol);
        __syncthreads();
        bf16x8 af[4], bfr[4];
        #pragma unroll
        for (int mt = 0; mt < 4; ++mt)
            af[mt] = *(const bf16x8*)(As + (wm * 64 + mt * 16 + lrow) * 32 + lquad * 8);
        #pragma unroll
        for (int nt = 0; nt < 4; ++nt)
            bfr[nt] = *(const bf16x8*)(Bs + (wn * 64 + nt * 16 + lrow) * 32 + lquad * 8);
        #pragma unroll
        for (int mt = 0; mt < 4; ++mt)
            #pragma unroll
            for (int nt = 0; nt < 4; ++nt)
                acc[mt][nt] = __builtin_amdgcn_mfma_f32_16x16x32_bf16(af[mt], bfr[nt], acc[mt][nt], 0, 0, 0);
        __syncthreads();
    }
    #pragma unroll
    for (int mt = 0; mt < 4; ++mt)
        #pragma unroll
        for (int nt = 0; nt < 4; ++nt) {
            int rowp = m0 + wm * 64 + mt * 16 + lquad * 4;
            int colp = n0 + wn * 64 + nt * 16 + lrow;
            eq(rowp, colp, acc[mt][nt]);
        }
}

// ---------------- V-transpose + QR GEMM in one launch ----------------
__global__ __launch_bounds__(256) void vtrans_qr_kernel(const u16* __restrict__ Vtmp, u16* __restrict__ VT,
                                                        const u16* __restrict__ Q, const u16* __restrict__ RWg,
                                                        u16* __restrict__ QR, const float* __restrict__ v) {
    __shared__ alignas(16) char smem[14336];   // gemm_bt_body needs 2*64*56*2 B
    int bid = blockIdx.x, tid = threadIdx.x;
    if (bid < 4096) {
        u16 (*tile)[34] = (u16(*)[34])smem;
        int t0 = (bid & 15) * 32, d0 = ((bid >> 4) & 1) * 32, bh = bid >> 5;
        int tx = tid & 31, ty = tid >> 5;
        const u16* src = Vtmp + (long)bh * 512 * 64;
        #pragma unroll
        for (int i = 0; i < 32; i += 8)
            tile[ty + i][tx] = src[(long)(t0 + ty + i) * 64 + d0 + tx];
        __syncthreads();
        u16* dst = VT + (long)bh * 64 * 512;
        #pragma unroll
        for (int i = 0; i < 32; i += 8)
            dst[(long)(d0 + ty + i) * 512 + t0 + tx] = tile[tx][ty + i];
        return;
    }
    int bid2 = bid - 4096;
    int bx = bid2 % 5;
    int rest = bid2 / 5;
    int by = rest & 31, bz = rest >> 5;
    gemm_bt_body<EpiStoreBf, false, true, false>(smem, bx, by, bz,
        (const void*)Q, 64, 2048L * 64, RWg, 1024, 64L, 64,
        EpiStoreBf{QR, 320, 2048L * 320}, v);
}

// ---------------- out-proj ----------------
__global__ __launch_bounds__(256) void outproj_kernel(const u16* __restrict__ A,
                                                      const u16* __restrict__ B,
                                                      float* __restrict__ out) {
    __shared__ alignas(16) char smem[14336];
    gemm_bt_body<EpiStoreF32, false, false, false>(smem, blockIdx.x, blockIdx.y, 0,
        (const void*)A, 1024, 0L, B, 1024, 0L, 1024, EpiStoreF32{out, 1024}, nullptr);
}

// ---------------- fused attention: 32 query rows per block ----------------
__global__ __launch_bounds__(256, 2) void attn_kernel(const u16* __restrict__ Qs,
                                                      const u16* __restrict__ Kt,
                                                      const u16* __restrict__ VT,
                                                      const u16* __restrict__ QR,
                                                      const float* __restrict__ uvec,
                                                      u16* __restrict__ attnOut) {
    constexpr int SLDB = 520;
    constexpr int QLD = 328;
    __shared__ alignas(16) u16 Sb[32 * SLDB];
    __shared__ alignas(16) u16 QRs[32 * QLD];
    __shared__ float red[2][4][32];
    int id = blockIdx.x;
    int bh = id & 127, it = id >> 7;
    int b = bh >> 4, h = bh & 15;
    int i0 = it * 32;
    int tid = threadIdx.x, wave = tid >> 6, lane = tid & 63;
    int lrow = lane & 15, lquad = lane >> 4;

    const u16* qrg = QR + ((long)h * 2048 + b * 256 + i0) * 320;
    #pragma unroll
    for (int kk = 0; kk < 5; ++kk) {
        int idx = tid + kk * 256;
        int row = idx / 40, c = idx - row * 40;
        *(bf16x8*)(QRs + row * QLD + c * 8) = *(const bf16x8*)(qrg + row * 320 + c * 8);
    }

    bf16x8 aq[2][2];
    #pragma unroll
    for (int iu = 0; iu < 2; ++iu) {
        const u16* qbase = Qs + (long)((h * 8 + b) * 256 + i0 + iu * 16 + lrow) * 64;
        aq[iu][0] = *(const bf16x8*)(qbase + lquad * 8);
        aq[iu][1] = *(const bf16x8*)(qbase + 32 + lquad * 8);
        #pragma unroll
        for (int j = 0; j < 8; ++j) {
            aq[iu][0][j] = (short)f2b(b2f((u16)aq[iu][0][j]) + 0.125f * uvec[lquad * 8 + j]);
            aq[iu][1][j] = (short)f2b(b2f((u16)aq[iu][1][j]) + 0.125f * uvec[32 + lquad * 8 + j]);
        }
    }

    const u16* kbase = Kt + (long)(bh * 512) * 64;
    f32x4 acc[2][8];
    #pragma unroll
    for (int half = 0; half < 2; ++half) {
        bf16x8 bk0[4], bk1[4];
        #pragma unroll
        for (int t = 0; t < 4; ++t) {
            const u16* kp = kbase + (long)(wave * 128 + (half * 4 + t) * 16 + lrow) * 64;
            bk0[t] = *(const bf16x8*)(kp + lquad * 8);
            bk1[t] = *(const bf16x8*)(kp + 32 + lquad * 8);
        }
        #pragma unroll
        for (int t = 0; t < 4; ++t)
            #pragma unroll
            for (int iu = 0; iu < 2; ++iu) {
                f32x4 a = {0.f, 0.f, 0.f, 0.f};
                a = __builtin_amdgcn_mfma_f32_16x16x32_bf16(aq[iu][0], bk0[t], a, 0, 0, 0);
                a = __builtin_amdgcn_mfma_f32_16x16x32_bf16(aq[iu][1], bk1[t], a, 0, 0, 0);
                acc[iu][half * 4 + t] = a;
            }
    }
    __syncthreads();

    float m4[2][4];
    #pragma unroll
    for (int iu = 0; iu < 2; ++iu)
        #pragma unroll
        for (int r = 0; r < 4; ++r) m4[iu][r] = -1e30f;
    #pragma unroll
    for (int jt = 0; jt < 8; ++jt) {
        int j = wave * 128 + jt * 16 + lrow;
        #pragma unroll
        for (int iu = 0; iu < 2; ++iu)
            #pragma unroll
            for (int r = 0; r < 4; ++r) {
                int rloc = iu * 16 + lquad * 4 + r;
                int i = i0 + rloc;
                int s = (j - i - 256) & 1023;
                int sc = (s >= 768) ? (s - 768) : 256;
                bool ok = (j >= 256) ? ((j - 256) <= i) : (j >= i);
                float val = ok ? acc[iu][jt][r] + b2f(QRs[rloc * QLD + sc]) : -1e30f;
                acc[iu][jt][r] = val;
                m4[iu][r] = fmaxf(m4[iu][r], val);
            }
    }
    #pragma unroll
    for (int iu = 0; iu < 2; ++iu)
        #pragma unroll
        for (int r = 0; r < 4; ++r) {
            #pragma unroll
            for (int off = 1; off < 16; off <<= 1)
                m4[iu][r] = fmaxf(m4[iu][r], __shfl_xor(m4[iu][r], off));
            if (lrow == 0) red[0][wave][iu * 16 + lquad * 4 + r] = m4[iu][r];
        }
    __syncthreads();

    float gmax[2][4];
    #pragma unroll
    for (int iu = 0; iu < 2; ++iu)
        #pragma unroll
        for (int r = 0; r < 4; ++r) {
            int row = iu * 16 + lquad * 4 + r;
            gmax[iu][r] = fmaxf(fmaxf(red[0][0][row], red[0][1][row]),
                                fmaxf(red[0][2][row], red[0][3][row]));
        }

    float s4[2][4] = {};
    #pragma unroll
    for (int jt = 0; jt < 8; ++jt) {
        int j = wave * 128 + jt * 16 + lrow;
        #pragma unroll
        for (int iu = 0; iu < 2; ++iu)
            #pragma unroll
            for (int r = 0; r < 4; ++r) {
                float p = __expf(acc[iu][jt][r] - gmax[iu][r]);
                s4[iu][r] += p;
                Sb[(iu * 16 + lquad * 4 + r) * SLDB + j] = f2b(p);
            }
    }
    #pragma unroll
    for (int iu = 0; iu < 2; ++iu)
        #pragma unroll
        for (int r = 0; r < 4; ++r) {
            #pragma unroll
            for (int off = 1; off < 16; off <<= 1)
                s4[iu][r] += __shfl_xor(s4[iu][r], off);
            if (lrow == 0) red[1][wave][iu * 16 + lquad * 4 + r] = s4[iu][r];
        }
    __syncthreads();

    const u16* vbase = VT + (long)(bh * 64 + wave * 16 + lrow) * 512;
    f32x4 oacc[2] = {};
    #pragma unroll
    for (int half = 0; half < 2; ++half) {
        bf16x8 vp[8];
        #pragma unroll
        for (int t = 0; t < 8; ++t)
            vp[t] = *(const bf16x8*)(vbase + (half * 8 + t) * 32 + lquad * 8);
        #pragma unroll
        for (int t = 0; t < 8; ++t)
            #pragma unroll
            for (int iu = 0; iu < 2; ++iu) {
                bf16x8 ap = *(const bf16x8*)(Sb + (iu * 16 + lrow) * SLDB + (half * 8 + t) * 32 + lquad * 8);
                oacc[iu] = __builtin_amdgcn_mfma_f32_16x16x32_bf16(ap, vp[t], oacc[iu], 0, 0, 0);
            }
    }
    #pragma unroll
    for (int iu = 0; iu < 2; ++iu)
        #pragma unroll
        for (int r = 0; r < 4; ++r) {
            int row = iu * 16 + lquad * 4 + r;
            float inv = 1.0f / (red[1][0][row] + red[1][1][row] + red[1][2][row] + red[1][3][row]);
            attnOut[(long)(b * 256 + i0 + row) * 1024 + h * 64 + wave * 16 + lrow] = f2b(oacc[iu][r] * inv);
        }
}

// ---------------- launch ----------------

extern "C" void kernel_launch(void* const* d_in, const int* in_sizes, int n_in,
                              void* d_out, int out_size, void* d_ws, size_t ws_size,
                              hipStream_t stream) {
    (void)in_sizes; (void)n_in; (void)out_size; (void)ws_size;
    const float* x    = (const float*)d_in[0];
    const float* h    = (const float*)d_in[1];
    const float* Wqkv = (const float*)d_in[2];
    const float* Wkr  = (const float*)d_in[3];
    const float* R    = (const float*)d_in[4];
    const float* u    = (const float*)d_in[5];
    const float* v    = (const float*)d_in[6];
    const float* Wout = (const float*)d_in[7];
    float* out = (float*)d_out;

    char* ws = (char*)d_ws;
    size_t off = 0;
    auto alloc = [&](size_t bytes) -> void* {
        void* p = ws + off;
        off = (off + bytes + 255) & ~(size_t)255;
        return p;
    };
    u16* catBF  = (u16*)alloc(4096L * 1024 * 2);   // [b*512][1024]
    u16* WqkvT  = (u16*)alloc(3072L * 1024 * 2);
    u16* WkrT   = (u16*)alloc(1024L * 1024 * 2);
    u16* WoutT  = (u16*)alloc(1024L * 1024 * 2);
    u16* RWg    = (u16*)alloc(320L * 1024 * 2);    // live shift rows of R@Wkr
    u16* Q      = (u16*)alloc(16L * 8 * 256 * 64 * 2);   // [h][b][i][d], 0.125*q
    u16* Kt     = (u16*)alloc(8L * 16 * 512 * 64 * 2);   // [b][h][t][d]
    u16* Vtmp   = (u16*)alloc(8L * 16 * 512 * 64 * 2);   // [b][h][t][d]
    u16* VT     = (u16*)alloc(8L * 16 * 64 * 512 * 2);   // [b][h][d][t]
    u16* QR     = (u16*)alloc(16L * 2048 * 320 * 2);     // [h][b*256+i][sc]
    u16* attnO  = (u16*)alloc(2048L * 1024 * 2);   // [b*256+i][h*64+d]

    prep_kernel<<<7168, 256, 0, stream>>>(x, h, catBF, Wqkv, WqkvT, Wkr, WkrT, Wout, WoutT);
    qkv_rwg_kernel<<<848, 256, 0, stream>>>(WqkvT, catBF, EpiQKV4{Q, Kt, Vtmp}, R, WkrT, RWg);
    vtrans_qr_kernel<<<6656, 256, 0, stream>>>(Vtmp, VT, Q, RWg, QR, v);
    attn_kernel<<<1024, 256, 0, stream>>>(Q, Kt, VT, QR, u, attnO);
    outproj_kernel<<<dim3(16, 32), 256, 0, stream>>>(attnO, WoutT, out);
}